// Round 11
// baseline (30.786 us; speedup 1.0000x reference)
//
#include <hip/hip_runtime.h>

#define LD4(p) (*reinterpret_cast<const float4*>(p))

__device__ __forceinline__ float dot16(float4 e0, float4 e1, float4 e2, float4 e3,
                                       float4 w0, float4 w1, float4 w2, float4 w3) {
    return e0.x*w0.x + e0.y*w0.y + e0.z*w0.z + e0.w*w0.w
         + e1.x*w1.x + e1.y*w1.y + e1.z*w1.z + e1.w*w1.w
         + e2.x*w2.x + e2.y*w2.y + e2.z*w2.z + e2.w*w2.w
         + e3.x*w3.x + e3.y*w3.y + e3.z*w3.z + e3.w*w3.w;
}

__device__ __forceinline__ float red16(float q) {
    q += __shfl_xor(q, 1, 16);
    q += __shfl_xor(q, 2, 16);
    q += __shfl_xor(q, 4, 16);
    q += __shfl_xor(q, 8, 16);
    return q;
}

__device__ __forceinline__ float bce_term(float q, float y, float m) {
    return m * (fmaxf(q, 0.0f) - q * y + __logf(1.0f + __expf(-fabsf(q))));
}

// Fully-parallel metadata linearization: one thread per (row, l).
// packed = idx | code<<17 | mask<<18   (idx <= V-2 < 2^17)
__global__ __launch_bounds__(256) void hs_pack(
    const int*   __restrict__ target,
    const int*   __restrict__ path_idx,
    const float* __restrict__ path_codes,
    const float* __restrict__ path_mask,
    int* __restrict__ packed,
    int NL, int L)
{
    const int i = blockIdx.x * blockDim.x + threadIdx.x;
    if (i >= NL) return;
    const int row = i / L;
    const int l   = i - row * L;
    const int t   = target[row];
    const size_t o = (size_t)t * L + l;
    const int idx = path_idx[o];
    const int c   = (path_codes[o] != 0.0f) ? 1 : 0;
    const int m   = (path_mask[o]  != 0.0f) ? 1 : 0;
    packed[i] = idx | (c << 17) | (m << 18);
}

// R8 structure: one wave per row, 4 groups of 16 lanes split the path.
// Metadata now comes from ONE coalesced load of the packed table.
__global__ __launch_bounds__(256) void hs_main(
    const float* __restrict__ emb,        // [N, 256]
    const float* __restrict__ fc,         // [V-1, 256]
    const int*   __restrict__ packed,     // [N, L]
    const float2* __restrict__ dummy,     // unused
    float2* __restrict__ partials,        // [gridDim.x]
    int N, int L)
{
    const int lane = threadIdx.x & 63;
    const int g    = lane >> 4;
    const int li   = lane & 15;
    const int wid  = threadIdx.x >> 6;
    const int gwave  = blockIdx.x * (blockDim.x >> 6) + wid;
    const int nwaves = gridDim.x * (blockDim.x >> 6);

    float bce_acc = 0.0f;   // per-lane copy of its group's sum
    float cnt_acc = 0.0f;   // wave-uniform

    for (int row = gwave; row < N; row += nwaves) {
        const float* erow = emb + (size_t)row * 256 + li * 16;
        const float4 e0 = LD4(erow), e1 = LD4(erow + 4),
                     e2 = LD4(erow + 8), e3 = LD4(erow + 12);

        // ONE load replaces target + 3 metadata gathers
        int p = 0;
        if (lane < L) p = packed[(size_t)row * L + lane];
        const int   pi = p & 0x1FFFF;
        const float pc = (float)((p >> 17) & 1);
        const float pm = (float)((p >> 18) & 1);

        const unsigned long long bal = __ballot(pm != 0.0f);
        const int plen = __popcll(bal);   // prefix mask, plen <= min(L,64)
        cnt_acc += (float)plen;

        for (int j4 = 0; j4 < plen; j4 += 8) {
            const int i0 = j4 + g;            // <= 63 always
            const int i1 = j4 + 4 + g;        // <= 63 always
            const int n0 = __shfl(pi, i0, 64);
            const int n1 = __shfl(pi, i1, 64);
            const float* p0 = fc + ((size_t)n0 << 8) + li * 16;
            const float* p1 = fc + ((size_t)n1 << 8) + li * 16;
            const float4 a0 = LD4(p0), a1 = LD4(p0 + 4),
                         a2 = LD4(p0 + 8), a3 = LD4(p0 + 12);
            const float4 b0 = LD4(p1), b1 = LD4(p1 + 4),
                         b2 = LD4(p1 + 8), b3 = LD4(p1 + 12);
            const float y0 = __shfl(pc, i0, 64);
            const float y1 = __shfl(pc, i1, 64);
            const float m0 = (i0 < plen) ? 1.0f : 0.0f;
            const float m1 = (i1 < plen) ? 1.0f : 0.0f;

            float q0 = dot16(e0, e1, e2, e3, a0, a1, a2, a3);
            float q1 = dot16(e0, e1, e2, e3, b0, b1, b2, b3);
            q0 = red16(q0);
            q1 = red16(q1);

            bce_acc += bce_term(q0, y0, m0);
            bce_acc += bce_term(q1, y1, m1);
        }
    }

    bce_acc += __shfl_xor(bce_acc, 16, 64);
    bce_acc += __shfl_xor(bce_acc, 32, 64);

    __shared__ float s_b[4], s_c[4];
    if (lane == 0) { s_b[wid] = bce_acc; s_c[wid] = cnt_acc; }
    __syncthreads();
    if (threadIdx.x == 0) {
        const int nw = blockDim.x >> 6;
        float b = 0.0f, c = 0.0f;
        for (int i = 0; i < nw; ++i) { b += s_b[i]; c += s_c[i]; }
        partials[blockIdx.x] = make_float2(b, c);
    }
}

__global__ __launch_bounds__(256) void hs_fin(
    const float2* __restrict__ partials, int nparts, float* __restrict__ out)
{
    double b = 0.0, c = 0.0;
    for (int i = threadIdx.x; i < nparts; i += blockDim.x) {
        const float2 p = partials[i];
        b += (double)p.x;
        c += (double)p.y;
    }
    __shared__ double sb[256], sc[256];
    sb[threadIdx.x] = b; sc[threadIdx.x] = c;
    __syncthreads();
    for (int s = 128; s > 0; s >>= 1) {
        if (threadIdx.x < s) {
            sb[threadIdx.x] += sb[threadIdx.x + s];
            sc[threadIdx.x] += sc[threadIdx.x + s];
        }
        __syncthreads();
    }
    if (threadIdx.x == 0) out[0] = (float)(sb[0] / sc[0]);
}

extern "C" void kernel_launch(void* const* d_in, const int* in_sizes, int n_in,
                              void* d_out, int out_size, void* d_ws, size_t ws_size,
                              hipStream_t stream) {
    const float* emb        = (const float*)d_in[0];
    const float* fc         = (const float*)d_in[1];
    const int*   target     = (const int*)d_in[2];
    const int*   path_idx   = (const int*)d_in[3];
    const float* path_codes = (const float*)d_in[4];
    const float* path_mask  = (const float*)d_in[5];

    const int N = in_sizes[2];
    const int V = in_sizes[1] / 256 + 1;
    const int L = in_sizes[3] / V;

    float*  out      = (float*)d_out;
    float2* partials = (float2*)d_ws;                      // 16 KB region
    int*    packed   = (int*)((char*)d_ws + 65536);        // [N, L]

    const int block = 256;
    int nblocks = (N + 3) / 4;             // 1 wave per row -> 8192 waves
    if (nblocks < 1) nblocks = 1;

    const int NL = N * L;
    const bool ok = ws_size >= 65536 + (size_t)NL * sizeof(int) &&
                    (size_t)nblocks * sizeof(float2) <= 65536;

    if (ok) {
        hs_pack<<<(NL + block - 1) / block, block, 0, stream>>>(
            target, path_idx, path_codes, path_mask, packed, NL, L);
        hs_main<<<nblocks, block, 0, stream>>>(emb, fc, packed, nullptr,
                                               partials, N, L);
        hs_fin<<<1, block, 0, stream>>>(partials, nblocks, out);
    } else {
        // should not happen (ws is large); degenerate safe path
        hs_pack<<<(NL + block - 1) / block, block, 0, stream>>>(
            target, path_idx, path_codes, path_mask, (int*)d_ws, NL, L);
        hs_main<<<nblocks, block, 0, stream>>>(emb, fc, (int*)d_ws, nullptr,
                                               (float2*)d_out, 1, L);
    }
}